// Round 1
// baseline (3273.534 us; speedup 1.0000x reference)
//
#include <hip/hip_runtime.h>
#include <math.h>

#define N_ENTITY 200000
#define EMBED    64
#define N_EDGES  6400000
#define BATCH    1024
#define QLEN     20
#define NNEG     5
#define NSEL     (BATCH + BATCH + BATCH*NNEG)   // 7168 gathered rows

// ---------------------------------------------------------------- SpMM -----
// One wave (64 lanes) per edge; lane = embed dim. Grid-stride over edges.
__global__ void spmm_kernel(const float* __restrict__ src, float* __restrict__ dst,
                            const int* __restrict__ erow, const int* __restrict__ ecol,
                            const float* __restrict__ evalv, int n_edges) {
    int lane  = threadIdx.x & 63;
    int wave  = blockIdx.x * (blockDim.x >> 6) + (threadIdx.x >> 6);
    int nwave = gridDim.x * (blockDim.x >> 6);
    for (int e = wave; e < n_edges; e += nwave) {
        int   r = erow[e];
        int   c = ecol[e];
        float v = evalv[e];
        float x = src[(size_t)c * EMBED + lane];
        atomicAdd(&dst[(size_t)r * EMBED + lane], v * x);
    }
}

// Layer-3 variant: only rows present in the sel bitmap are ever read again.
__global__ void spmm_filtered_kernel(const float* __restrict__ src, float* __restrict__ dst,
                                     const int* __restrict__ erow, const int* __restrict__ ecol,
                                     const float* __restrict__ evalv,
                                     const unsigned int* __restrict__ bm, int n_edges) {
    int lane  = threadIdx.x & 63;
    int wave  = blockIdx.x * (blockDim.x >> 6) + (threadIdx.x >> 6);
    int nwave = gridDim.x * (blockDim.x >> 6);
    for (int e = wave; e < n_edges; e += nwave) {
        int r = erow[e];
        if (!((bm[r >> 5] >> (r & 31)) & 1u)) continue;   // wave-uniform skip
        int   c = ecol[e];
        float v = evalv[e];
        float x = src[(size_t)c * EMBED + lane];
        atomicAdd(&dst[(size_t)r * EMBED + lane], v * x);
    }
}

// ------------------------------------------------- sel gather/accumulate ---
// sel rows: [0,1024)=users, [1024,2048)=items, [2048,7168)=neg_items (flat).
__global__ void sel_accum_kernel(const float* __restrict__ h,
                                 const int* __restrict__ users,
                                 const int* __restrict__ items,
                                 const int* __restrict__ negs,
                                 float* __restrict__ sel, int init) {
    int tid = blockIdx.x * blockDim.x + threadIdx.x;
    if (tid >= NSEL * EMBED) return;
    int i = tid >> 6;
    int d = tid & 63;
    int idx;
    if (i < BATCH)          idx = users[i];
    else if (i < 2*BATCH)   idx = items[i - BATCH];
    else                    idx = negs[i - 2*BATCH];
    float v = h[(size_t)idx * EMBED + d];
    if (init) sel[tid] = v;
    else      sel[tid] += v;
}

__global__ void bitmap_build_kernel(const int* __restrict__ users,
                                    const int* __restrict__ items,
                                    const int* __restrict__ negs,
                                    unsigned int* __restrict__ bm) {
    int i = blockIdx.x * blockDim.x + threadIdx.x;
    if (i >= NSEL) return;
    int idx;
    if (i < BATCH)          idx = users[i];
    else if (i < 2*BATCH)   idx = items[i - BATCH];
    else                    idx = negs[i - 2*BATCH];
    atomicOr(&bm[idx >> 5], 1u << (idx & 31));
}

// -------------------------------------------------------- sentence encode --
// One block (128 threads) per batch element. All f32 in LDS.
__global__ void sent_kernel(const int* __restrict__ qwords,
                            const float* __restrict__ word_w,
                            const float* __restrict__ Win,  const float* __restrict__ bin,
                            const float* __restrict__ Wout, const float* __restrict__ bout,
                            float* __restrict__ qenc) {
    __shared__ float x[QLEN][EMBED];
    __shared__ float qkv[QLEN][3*EMBED];
    __shared__ float ctx[QLEN][EMBED];
    __shared__ float mctx[EMBED];
    int b = blockIdx.x;
    int t = threadIdx.x;   // 0..127

    for (int j = t; j < QLEN*EMBED; j += 128) {
        int q = j >> 6, d = j & 63;
        int w = qwords[b*QLEN + q];
        x[q][d] = word_w[(size_t)w * EMBED + d];
    }
    __syncthreads();

    // qkv = x @ Win^T + bin   (20 x 192)
    for (int j = t; j < QLEN*192; j += 128) {
        int q = j / 192, o = j % 192;
        float acc = bin[o];
        const float* wrow = &Win[o*EMBED];
        #pragma unroll
        for (int d = 0; d < EMBED; ++d) acc += x[q][d] * wrow[d];
        qkv[q][o] = acc;
    }
    __syncthreads();

    // attention: 4 heads x 20 query rows = 80 independent rows
    if (t < 4*QLEN) {
        int h = t / QLEN, i = t % QLEN;
        float sc[QLEN];
        float mx = -1e30f;
        #pragma unroll
        for (int k = 0; k < QLEN; ++k) {
            float s = 0.f;
            #pragma unroll
            for (int d = 0; d < 16; ++d)
                s += qkv[i][h*16 + d] * qkv[k][EMBED + h*16 + d];
            s *= 0.25f;                       // 1/sqrt(16)
            sc[k] = s;
            mx = fmaxf(mx, s);
        }
        float denom = 0.f;
        #pragma unroll
        for (int k = 0; k < QLEN; ++k) { sc[k] = expf(sc[k] - mx); denom += sc[k]; }
        float inv = 1.0f / denom;
        #pragma unroll
        for (int d = 0; d < 16; ++d) {
            float acc = 0.f;
            #pragma unroll
            for (int k = 0; k < QLEN; ++k)
                acc += sc[k] * qkv[k][2*EMBED + h*16 + d];
            ctx[i][h*16 + d] = acc * inv;
        }
    }
    __syncthreads();

    // mean over q (linear => mean before out-proj)
    if (t < EMBED) {
        float acc = 0.f;
        #pragma unroll
        for (int q = 0; q < QLEN; ++q) acc += ctx[q][t];
        mctx[t] = acc * (1.0f/QLEN);
    }
    __syncthreads();

    if (t < EMBED) {
        float acc = bout[t];
        const float* wrow = &Wout[t*EMBED];
        #pragma unroll
        for (int d = 0; d < EMBED; ++d) acc += mctx[d] * wrow[d];
        qenc[b*EMBED + t] = acc;
    }
}

// ----------------------------------------------------------------- losses --
__device__ __forceinline__ float log_sigmoid(float x) {
    float l = log1pf(expf(-fabsf(x)));
    return x >= 0.f ? -l : x - l;
}
__device__ __forceinline__ float wred(float v) {
    #pragma unroll
    for (int off = 32; off; off >>= 1) v += __shfl_xor(v, off);
    return v;
}

__global__ void loss_kernel(const float* __restrict__ sel,
                            const float* __restrict__ qenc,
                            float* __restrict__ out) {
    int b = blockIdx.x;
    int d = threadIdx.x;   // 0..63, one wave
    const float scale = 0.25f;   // / (CONV_NUM + 1)
    float u   = sel[(size_t)b*EMBED + d] * scale;
    float pos = sel[(size_t)(BATCH + b)*EMBED + d] * scale;
    float p   = qenc[b*EMBED + d] + 0.1f * u;

    float s_up = wred(u * pos);
    float s_pp = wred(p * pos);
    float nu[NNEG], np_[NNEG];
    #pragma unroll
    for (int n = 0; n < NNEG; ++n) {
        float ng = sel[(size_t)(2*BATCH + b*NNEG + n)*EMBED + d] * scale;
        nu[n]  = wred(u * ng);
        np_[n] = wred(p * ng);
    }
    if (d == 0) {
        float cf = 0.f, srch_neg = 0.f;
        #pragma unroll
        for (int n = 0; n < NNEG; ++n) {
            cf       += -log_sigmoid(s_up - nu[n]);
            srch_neg += -log_sigmoid(-np_[n]);
        }
        float res = cf * (1.0f/(BATCH*NNEG))
                  + (-log_sigmoid(s_pp)) * (1.0f/BATCH)
                  + srch_neg * (1.0f/(BATCH*NNEG));
        atomicAdd(out, res);
    }
}

// ---------------------------------------------------------------- launch ---
extern "C" void kernel_launch(void* const* d_in, const int* in_sizes, int n_in,
                              void* d_out, int out_size, void* d_ws, size_t ws_size,
                              hipStream_t stream) {
    const float* entity_w   = (const float*)d_in[0];
    const float* word_w     = (const float*)d_in[1];
    const float* in_proj_w  = (const float*)d_in[2];
    const float* in_proj_b  = (const float*)d_in[3];
    const float* out_proj_w = (const float*)d_in[4];
    const float* out_proj_b = (const float*)d_in[5];
    const float* edge_val   = (const float*)d_in[6];
    const int*   users      = (const int*)d_in[7];
    const int*   items      = (const int*)d_in[8];
    const int*   qwords     = (const int*)d_in[9];
    const int*   neg_items  = (const int*)d_in[10];
    const int*   edge_row   = (const int*)d_in[11];
    const int*   edge_col   = (const int*)d_in[12];
    float* out = (float*)d_out;

    const size_t HN = (size_t)N_ENTITY * EMBED;          // 12.8M floats
    float* hA   = (float*)d_ws;
    float* hB   = hA + HN;
    float* sel  = hB + HN;
    float* qenc = sel + (size_t)NSEL * EMBED;
    unsigned int* bm = (unsigned int*)(qenc + (size_t)BATCH * EMBED);
    const int BM_WORDS = (N_ENTITY + 31) / 32;

    hipMemsetAsync(out, 0, sizeof(float)*out_size, stream);
    hipMemsetAsync(bm, 0, sizeof(unsigned int)*BM_WORDS, stream);
    bitmap_build_kernel<<<(NSEL+255)/256, 256, 0, stream>>>(users, items, neg_items, bm);

    // layer 0 contribution
    sel_accum_kernel<<<(NSEL*EMBED)/256, 256, 0, stream>>>(entity_w, users, items, neg_items, sel, 1);

    // layer 1: entity_w -> hA
    hipMemsetAsync(hA, 0, HN*sizeof(float), stream);
    spmm_kernel<<<2048, 256, 0, stream>>>(entity_w, hA, edge_row, edge_col, edge_val, N_EDGES);
    sel_accum_kernel<<<(NSEL*EMBED)/256, 256, 0, stream>>>(hA, users, items, neg_items, sel, 0);

    // layer 2: hA -> hB
    hipMemsetAsync(hB, 0, HN*sizeof(float), stream);
    spmm_kernel<<<2048, 256, 0, stream>>>(hA, hB, edge_row, edge_col, edge_val, N_EDGES);
    sel_accum_kernel<<<(NSEL*EMBED)/256, 256, 0, stream>>>(hB, users, items, neg_items, sel, 0);

    // layer 3: hB -> hA, only rows we will read back
    hipMemsetAsync(hA, 0, HN*sizeof(float), stream);
    spmm_filtered_kernel<<<2048, 256, 0, stream>>>(hB, hA, edge_row, edge_col, edge_val, bm, N_EDGES);
    sel_accum_kernel<<<(NSEL*EMBED)/256, 256, 0, stream>>>(hA, users, items, neg_items, sel, 0);

    // sentence encoder
    sent_kernel<<<BATCH, 128, 0, stream>>>(qwords, word_w, in_proj_w, in_proj_b,
                                           out_proj_w, out_proj_b, qenc);

    // losses -> scalar
    loss_kernel<<<BATCH, 64, 0, stream>>>(sel, qenc, out);
}

// Round 2
// 1190.386 us; speedup vs baseline: 2.7500x; 2.7500x over previous
//
#include <hip/hip_runtime.h>
#include <math.h>

#define N_ENTITY 200000
#define EMBED    64
#define N_EDGES  6400000
#define BATCH    1024
#define QLEN     20
#define NNEG     5
#define NSEL     (BATCH + BATCH + BATCH*NNEG)   // 7168 gathered rows
#define BM_WORDS ((N_ENTITY + 31) / 32)

#define SCAN_T   256
#define SCAN_E   1024   // elems per scan block (256 threads x 4)
#define SCAN_NB  ((N_ENTITY + SCAN_E - 1) / SCAN_E)   // 196

// ------------------------------------------------------------- CSR build ---
__global__ void hist_kernel(const int* __restrict__ erow, int* __restrict__ cnt) {
    int tid = blockIdx.x * blockDim.x + threadIdx.x;
    int n   = gridDim.x * blockDim.x;
    for (int e = tid; e < N_EDGES; e += n) atomicAdd(&cnt[erow[e]], 1);
}

__global__ void scan_blocks_kernel(const int* __restrict__ cnt, int* __restrict__ part,
                                   int* __restrict__ bsum) {
    __shared__ int s[SCAN_T];
    int blk = blockIdx.x, t = threadIdx.x;
    int base = blk * SCAN_E + t * 4;
    int v[4];
    #pragma unroll
    for (int k = 0; k < 4; ++k) { int i = base + k; v[k] = (i < N_ENTITY) ? cnt[i] : 0; }
    int tsum = v[0] + v[1] + v[2] + v[3];
    s[t] = tsum; __syncthreads();
    for (int off = 1; off < SCAN_T; off <<= 1) {
        int x = (t >= off) ? s[t - off] : 0;
        __syncthreads();
        s[t] += x;
        __syncthreads();
    }
    int excl = t ? s[t - 1] : 0;
    if (t == SCAN_T - 1) bsum[blk] = s[t];
    int run = excl;
    #pragma unroll
    for (int k = 0; k < 4; ++k) { int i = base + k; if (i < N_ENTITY) part[i] = run; run += v[k]; }
}

__global__ void scan_top_kernel(int* __restrict__ bsum) {
    __shared__ int s[SCAN_T];
    int t = threadIdx.x;
    s[t] = (t < SCAN_NB) ? bsum[t] : 0;
    __syncthreads();
    for (int off = 1; off < SCAN_T; off <<= 1) {
        int x = (t >= off) ? s[t - off] : 0;
        __syncthreads();
        s[t] += x;
        __syncthreads();
    }
    if (t < SCAN_NB) bsum[t] = t ? s[t - 1] : 0;   // exclusive
}

__global__ void scan_add_kernel(int* __restrict__ rowptr, int* __restrict__ cursor,
                                const int* __restrict__ bsum) {
    int blk = blockIdx.x, t = threadIdx.x;
    int add = bsum[blk];
    int base = blk * SCAN_E + t * 4;
    #pragma unroll
    for (int k = 0; k < 4; ++k) {
        int i = base + k;
        if (i < N_ENTITY) { int v = rowptr[i] + add; rowptr[i] = v; cursor[i] = v; }
    }
    if (blk == 0 && t == 0) rowptr[N_ENTITY] = N_EDGES;
}

__global__ void scatter_kernel(const int* __restrict__ erow, const int* __restrict__ ecol,
                               const float* __restrict__ evalv,
                               int* __restrict__ cursor, int2* __restrict__ edges_s) {
    int tid = blockIdx.x * blockDim.x + threadIdx.x;
    int n   = gridDim.x * blockDim.x;
    for (int e = tid; e < N_EDGES; e += n) {
        int r   = erow[e];
        int pos = atomicAdd(&cursor[r], 1);
        edges_s[pos] = make_int2(ecol[e], __float_as_int(evalv[e]));
    }
}

// -------------------------------------------------------------- CSR SpMM ---
// One wave per row; lane = embed dim. Unroll-4 edge loads to overlap latency.
__global__ void spmm_csr_kernel(const float* __restrict__ src, float* __restrict__ dst,
                                const int* __restrict__ rowptr,
                                const int2* __restrict__ edges,
                                const unsigned int* __restrict__ bm) {
    int lane  = threadIdx.x & 63;
    int wave  = blockIdx.x * (blockDim.x >> 6) + (threadIdx.x >> 6);
    int nwave = gridDim.x * (blockDim.x >> 6);
    for (int row = wave; row < N_ENTITY; row += nwave) {
        if (bm && !((bm[row >> 5] >> (row & 31)) & 1u)) continue;
        int beg = rowptr[row], end = rowptr[row + 1];
        float acc = 0.f;
        int j = beg;
        for (; j + 4 <= end; j += 4) {
            int2 e0 = edges[j], e1 = edges[j+1], e2 = edges[j+2], e3 = edges[j+3];
            float x0 = src[(size_t)e0.x * EMBED + lane];
            float x1 = src[(size_t)e1.x * EMBED + lane];
            float x2 = src[(size_t)e2.x * EMBED + lane];
            float x3 = src[(size_t)e3.x * EMBED + lane];
            acc += __int_as_float(e0.y) * x0;
            acc += __int_as_float(e1.y) * x1;
            acc += __int_as_float(e2.y) * x2;
            acc += __int_as_float(e3.y) * x3;
        }
        for (; j < end; ++j) {
            int2 e = edges[j];
            acc += __int_as_float(e.y) * src[(size_t)e.x * EMBED + lane];
        }
        dst[(size_t)row * EMBED + lane] = acc;
    }
}

// ---------------------------------------------- sel helpers / bitmaps ------
__device__ __forceinline__ int sel_row(int i, const int* users, const int* items,
                                       const int* negs) {
    if (i < BATCH)        return users[i];
    if (i < 2 * BATCH)    return items[i - BATCH];
    return negs[i - 2 * BATCH];
}

__global__ void sel_accum_kernel(const float* __restrict__ h,
                                 const int* __restrict__ users,
                                 const int* __restrict__ items,
                                 const int* __restrict__ negs,
                                 float* __restrict__ sel, int init) {
    int tid = blockIdx.x * blockDim.x + threadIdx.x;
    if (tid >= NSEL * EMBED) return;
    int i = tid >> 6, d = tid & 63;
    int idx = sel_row(i, users, items, negs);
    float v = h[(size_t)idx * EMBED + d];
    if (init) sel[tid] = v;
    else      sel[tid] += v;
}

// mark sel rows + all their neighbor cols (rows where h2 is needed)
__global__ void need_build_kernel(const int* __restrict__ users,
                                  const int* __restrict__ items,
                                  const int* __restrict__ negs,
                                  const int* __restrict__ rowptr,
                                  const int2* __restrict__ edges,
                                  unsigned int* __restrict__ bm) {
    int lane = threadIdx.x & 63;
    int wave = blockIdx.x * (blockDim.x >> 6) + (threadIdx.x >> 6);
    if (wave >= NSEL) return;
    int idx = sel_row(wave, users, items, negs);
    if (lane == 0) atomicOr(&bm[idx >> 5], 1u << (idx & 31));
    int beg = rowptr[idx], end = rowptr[idx + 1];
    for (int j = beg + lane; j < end; j += 64) {
        int c = edges[j].x;
        atomicOr(&bm[c >> 5], 1u << (c & 31));
    }
}

// layer-3 direct pull: sel[i] += sum_j val * h2[col]
__global__ void sel_pull_kernel(const float* __restrict__ h,
                                const int* __restrict__ users,
                                const int* __restrict__ items,
                                const int* __restrict__ negs,
                                const int* __restrict__ rowptr,
                                const int2* __restrict__ edges,
                                float* __restrict__ sel) {
    int lane = threadIdx.x & 63;
    int wave = blockIdx.x * (blockDim.x >> 6) + (threadIdx.x >> 6);
    if (wave >= NSEL) return;
    int idx = sel_row(wave, users, items, negs);
    int beg = rowptr[idx], end = rowptr[idx + 1];
    float acc = 0.f;
    int j = beg;
    for (; j + 2 <= end; j += 2) {
        int2 e0 = edges[j], e1 = edges[j+1];
        acc += __int_as_float(e0.y) * h[(size_t)e0.x * EMBED + lane];
        acc += __int_as_float(e1.y) * h[(size_t)e1.x * EMBED + lane];
    }
    for (; j < end; ++j) {
        int2 e = edges[j];
        acc += __int_as_float(e.y) * h[(size_t)e.x * EMBED + lane];
    }
    sel[(size_t)wave * EMBED + lane] += acc;
}

// --------------------------------------- fallback (round-1 atomic) path ----
__global__ void spmm_kernel(const float* __restrict__ src, float* __restrict__ dst,
                            const int* __restrict__ erow, const int* __restrict__ ecol,
                            const float* __restrict__ evalv, int n_edges) {
    int lane  = threadIdx.x & 63;
    int wave  = blockIdx.x * (blockDim.x >> 6) + (threadIdx.x >> 6);
    int nwave = gridDim.x * (blockDim.x >> 6);
    for (int e = wave; e < n_edges; e += nwave) {
        int   r = erow[e];
        int   c = ecol[e];
        float v = evalv[e];
        float x = src[(size_t)c * EMBED + lane];
        atomicAdd(&dst[(size_t)r * EMBED + lane], v * x);
    }
}

__global__ void spmm_filtered_kernel(const float* __restrict__ src, float* __restrict__ dst,
                                     const int* __restrict__ erow, const int* __restrict__ ecol,
                                     const float* __restrict__ evalv,
                                     const unsigned int* __restrict__ bm, int n_edges) {
    int lane  = threadIdx.x & 63;
    int wave  = blockIdx.x * (blockDim.x >> 6) + (threadIdx.x >> 6);
    int nwave = gridDim.x * (blockDim.x >> 6);
    for (int e = wave; e < n_edges; e += nwave) {
        int r = erow[e];
        if (!((bm[r >> 5] >> (r & 31)) & 1u)) continue;
        int   c = ecol[e];
        float v = evalv[e];
        float x = src[(size_t)c * EMBED + lane];
        atomicAdd(&dst[(size_t)r * EMBED + lane], v * x);
    }
}

__global__ void bitmap_build_kernel(const int* __restrict__ users,
                                    const int* __restrict__ items,
                                    const int* __restrict__ negs,
                                    unsigned int* __restrict__ bm) {
    int i = blockIdx.x * blockDim.x + threadIdx.x;
    if (i >= NSEL) return;
    int idx = sel_row(i, users, items, negs);
    atomicOr(&bm[idx >> 5], 1u << (idx & 31));
}

// -------------------------------------------------------- sentence encode --
__global__ void sent_kernel(const int* __restrict__ qwords,
                            const float* __restrict__ word_w,
                            const float* __restrict__ Win,  const float* __restrict__ bin,
                            const float* __restrict__ Wout, const float* __restrict__ bout,
                            float* __restrict__ qenc) {
    __shared__ float x[QLEN][EMBED];
    __shared__ float qkv[QLEN][3*EMBED];
    __shared__ float ctx[QLEN][EMBED];
    __shared__ float mctx[EMBED];
    int b = blockIdx.x;
    int t = threadIdx.x;   // 0..127

    for (int j = t; j < QLEN*EMBED; j += 128) {
        int q = j >> 6, d = j & 63;
        int w = qwords[b*QLEN + q];
        x[q][d] = word_w[(size_t)w * EMBED + d];
    }
    __syncthreads();

    for (int j = t; j < QLEN*192; j += 128) {
        int q = j / 192, o = j % 192;
        float acc = bin[o];
        const float* wrow = &Win[o*EMBED];
        #pragma unroll
        for (int d = 0; d < EMBED; ++d) acc += x[q][d] * wrow[d];
        qkv[q][o] = acc;
    }
    __syncthreads();

    if (t < 4*QLEN) {
        int h = t / QLEN, i = t % QLEN;
        float sc[QLEN];
        float mx = -1e30f;
        #pragma unroll
        for (int k = 0; k < QLEN; ++k) {
            float s = 0.f;
            #pragma unroll
            for (int d = 0; d < 16; ++d)
                s += qkv[i][h*16 + d] * qkv[k][EMBED + h*16 + d];
            s *= 0.25f;
            sc[k] = s;
            mx = fmaxf(mx, s);
        }
        float denom = 0.f;
        #pragma unroll
        for (int k = 0; k < QLEN; ++k) { sc[k] = expf(sc[k] - mx); denom += sc[k]; }
        float inv = 1.0f / denom;
        #pragma unroll
        for (int d = 0; d < 16; ++d) {
            float acc = 0.f;
            #pragma unroll
            for (int k = 0; k < QLEN; ++k)
                acc += sc[k] * qkv[k][2*EMBED + h*16 + d];
            ctx[i][h*16 + d] = acc * inv;
        }
    }
    __syncthreads();

    if (t < EMBED) {
        float acc = 0.f;
        #pragma unroll
        for (int q = 0; q < QLEN; ++q) acc += ctx[q][t];
        mctx[t] = acc * (1.0f/QLEN);
    }
    __syncthreads();

    if (t < EMBED) {
        float acc = bout[t];
        const float* wrow = &Wout[t*EMBED];
        #pragma unroll
        for (int d = 0; d < EMBED; ++d) acc += mctx[d] * wrow[d];
        qenc[b*EMBED + t] = acc;
    }
}

// ----------------------------------------------------------------- losses --
__device__ __forceinline__ float log_sigmoid(float x) {
    float l = log1pf(expf(-fabsf(x)));
    return x >= 0.f ? -l : x - l;
}
__device__ __forceinline__ float wred(float v) {
    #pragma unroll
    for (int off = 32; off; off >>= 1) v += __shfl_xor(v, off);
    return v;
}

__global__ void loss_kernel(const float* __restrict__ sel,
                            const float* __restrict__ qenc,
                            float* __restrict__ out) {
    int b = blockIdx.x;
    int d = threadIdx.x;   // 0..63
    const float scale = 0.25f;
    float u   = sel[(size_t)b*EMBED + d] * scale;
    float pos = sel[(size_t)(BATCH + b)*EMBED + d] * scale;
    float p   = qenc[b*EMBED + d] + 0.1f * u;

    float s_up = wred(u * pos);
    float s_pp = wred(p * pos);
    float nu[NNEG], np_[NNEG];
    #pragma unroll
    for (int n = 0; n < NNEG; ++n) {
        float ng = sel[(size_t)(2*BATCH + b*NNEG + n)*EMBED + d] * scale;
        nu[n]  = wred(u * ng);
        np_[n] = wred(p * ng);
    }
    if (d == 0) {
        float cf = 0.f, srch_neg = 0.f;
        #pragma unroll
        for (int n = 0; n < NNEG; ++n) {
            cf       += -log_sigmoid(s_up - nu[n]);
            srch_neg += -log_sigmoid(-np_[n]);
        }
        float res = cf * (1.0f/(BATCH*NNEG))
                  + (-log_sigmoid(s_pp)) * (1.0f/BATCH)
                  + srch_neg * (1.0f/(BATCH*NNEG));
        atomicAdd(out, res);
    }
}

// ---------------------------------------------------------------- launch ---
extern "C" void kernel_launch(void* const* d_in, const int* in_sizes, int n_in,
                              void* d_out, int out_size, void* d_ws, size_t ws_size,
                              hipStream_t stream) {
    const float* entity_w   = (const float*)d_in[0];
    const float* word_w     = (const float*)d_in[1];
    const float* in_proj_w  = (const float*)d_in[2];
    const float* in_proj_b  = (const float*)d_in[3];
    const float* out_proj_w = (const float*)d_in[4];
    const float* out_proj_b = (const float*)d_in[5];
    const float* edge_val   = (const float*)d_in[6];
    const int*   users      = (const int*)d_in[7];
    const int*   items      = (const int*)d_in[8];
    const int*   qwords     = (const int*)d_in[9];
    const int*   neg_items  = (const int*)d_in[10];
    const int*   edge_row   = (const int*)d_in[11];
    const int*   edge_col   = (const int*)d_in[12];
    float* out = (float*)d_out;

    const size_t HN = (size_t)N_ENTITY * EMBED;

    // CSR-path workspace layout (8B-aligned first)
    size_t need = sizeof(int2) * (size_t)N_EDGES          // edges_s
                + sizeof(float) * HN * 2                  // hA, hB
                + sizeof(float) * (size_t)NSEL * EMBED    // sel
                + sizeof(float) * (size_t)BATCH * EMBED   // qenc
                + sizeof(int) * (size_t)(N_ENTITY + 1)    // rowptr
                + sizeof(int) * (size_t)N_ENTITY          // cursor
                + sizeof(int) * 256                       // bsum
                + sizeof(unsigned int) * (size_t)BM_WORDS;// bmNeed

    hipMemsetAsync(out, 0, sizeof(float) * out_size, stream);

    if (ws_size >= need) {
        int2*  edges_s = (int2*)d_ws;
        float* hA      = (float*)(edges_s + N_EDGES);
        float* hB      = hA + HN;
        float* sel     = hB + HN;
        float* qenc    = sel + (size_t)NSEL * EMBED;
        int*   rowptr  = (int*)(qenc + (size_t)BATCH * EMBED);
        int*   cursor  = rowptr + N_ENTITY + 1;
        int*   bsum    = cursor + N_ENTITY;
        unsigned int* bmNeed = (unsigned int*)(bsum + 256);

        // --- CSR build ---
        hipMemsetAsync(cursor, 0, sizeof(int) * N_ENTITY, stream);
        hist_kernel<<<2048, 256, 0, stream>>>(edge_row, cursor);
        scan_blocks_kernel<<<SCAN_NB, SCAN_T, 0, stream>>>(cursor, rowptr, bsum);
        scan_top_kernel<<<1, SCAN_T, 0, stream>>>(bsum);
        scan_add_kernel<<<SCAN_NB, SCAN_T, 0, stream>>>(rowptr, cursor, bsum);
        scatter_kernel<<<2048, 256, 0, stream>>>(edge_row, edge_col, edge_val,
                                                 cursor, edges_s);

        // --- needed-rows bitmap for layer 2 ---
        hipMemsetAsync(bmNeed, 0, sizeof(unsigned int) * BM_WORDS, stream);
        need_build_kernel<<<(NSEL + 3) / 4, 256, 0, stream>>>(
            users, items, neg_items, rowptr, edges_s, bmNeed);

        // --- layer 0 ---
        sel_accum_kernel<<<(NSEL * EMBED) / 256, 256, 0, stream>>>(
            entity_w, users, items, neg_items, sel, 1);

        // --- layer 1: full ---
        spmm_csr_kernel<<<2048, 256, 0, stream>>>(entity_w, hA, rowptr, edges_s, nullptr);
        sel_accum_kernel<<<(NSEL * EMBED) / 256, 256, 0, stream>>>(
            hA, users, items, neg_items, sel, 0);

        // --- layer 2: needed rows only ---
        spmm_csr_kernel<<<2048, 256, 0, stream>>>(hA, hB, rowptr, edges_s, bmNeed);
        sel_accum_kernel<<<(NSEL * EMBED) / 256, 256, 0, stream>>>(
            hB, users, items, neg_items, sel, 0);

        // --- layer 3: direct pull into sel ---
        sel_pull_kernel<<<(NSEL + 3) / 4, 256, 0, stream>>>(
            hB, users, items, neg_items, rowptr, edges_s, sel);

        sent_kernel<<<BATCH, 128, 0, stream>>>(qwords, word_w, in_proj_w, in_proj_b,
                                               out_proj_w, out_proj_b, qenc);
        loss_kernel<<<BATCH, 64, 0, stream>>>(sel, qenc, out);
    } else {
        // -------- fallback: round-1 atomic path (~105 MB ws) --------
        float* hA   = (float*)d_ws;
        float* hB   = hA + HN;
        float* sel  = hB + HN;
        float* qenc = sel + (size_t)NSEL * EMBED;
        unsigned int* bm = (unsigned int*)(qenc + (size_t)BATCH * EMBED);

        hipMemsetAsync(bm, 0, sizeof(unsigned int) * BM_WORDS, stream);
        bitmap_build_kernel<<<(NSEL + 255) / 256, 256, 0, stream>>>(users, items, neg_items, bm);
        sel_accum_kernel<<<(NSEL * EMBED) / 256, 256, 0, stream>>>(
            entity_w, users, items, neg_items, sel, 1);
        hipMemsetAsync(hA, 0, HN * sizeof(float), stream);
        spmm_kernel<<<2048, 256, 0, stream>>>(entity_w, hA, edge_row, edge_col, edge_val, N_EDGES);
        sel_accum_kernel<<<(NSEL * EMBED) / 256, 256, 0, stream>>>(
            hA, users, items, neg_items, sel, 0);
        hipMemsetAsync(hB, 0, HN * sizeof(float), stream);
        spmm_kernel<<<2048, 256, 0, stream>>>(hA, hB, edge_row, edge_col, edge_val, N_EDGES);
        sel_accum_kernel<<<(NSEL * EMBED) / 256, 256, 0, stream>>>(
            hB, users, items, neg_items, sel, 0);
        hipMemsetAsync(hA, 0, HN * sizeof(float), stream);
        spmm_filtered_kernel<<<2048, 256, 0, stream>>>(hB, hA, edge_row, edge_col, edge_val, bm, N_EDGES);
        sel_accum_kernel<<<(NSEL * EMBED) / 256, 256, 0, stream>>>(
            hA, users, items, neg_items, sel, 0);
        sent_kernel<<<BATCH, 128, 0, stream>>>(qwords, word_w, in_proj_w, in_proj_b,
                                               out_proj_w, out_proj_b, qenc);
        loss_kernel<<<BATCH, 64, 0, stream>>>(sel, qenc, out);
    }
}